// Round 8
// baseline (462.341 us; speedup 1.0000x reference)
//
#include <hip/hip_runtime.h>

typedef unsigned short u16;
typedef unsigned int u32;
typedef __bf16 bf16x8 __attribute__((ext_vector_type(8)));
typedef float f32x4 __attribute__((ext_vector_type(4)));
typedef float f32x16 __attribute__((ext_vector_type(16)));

__device__ __forceinline__ u16 f2bf(float f) {
  u32 u = __builtin_bit_cast(u32, f);
  u = (u + 0x7fffu + ((u >> 16) & 1u)) >> 16;
  return (u16)u;
}
__device__ __forceinline__ float bf2f(u16 h) {
  return __builtin_bit_cast(float, ((u32)h) << 16);
}

// async global->LDS, 16B per lane; LDS dest = wave-uniform base + lane*16 [m97/m104]
__device__ __forceinline__ void gll16(const u16* g, u16* l) {
  __builtin_amdgcn_global_load_lds((const __attribute__((address_space(1))) void*)g,
                                   (__attribute__((address_space(3))) void*)l, 16, 0, 0);
}

// raw barrier: NO implicit vmcnt drain (the whole point of the counted pipeline)
__device__ __forceinline__ void barrier() {
  asm volatile("" ::: "memory");
  __builtin_amdgcn_s_barrier();
  asm volatile("" ::: "memory");
}
__device__ __forceinline__ void waitv3() { asm volatile("s_waitcnt vmcnt(3)" ::: "memory"); }
__device__ __forceinline__ void waitv0() { asm volatile("s_waitcnt vmcnt(0)" ::: "memory"); }

// ---------------- all fp32 -> bf16 conversions in one launch ----------------
__global__ __launch_bounds__(256) void cvt_all(const float* __restrict__ x,
                                               const float* __restrict__ WQ,
                                               const float* __restrict__ WK,
                                               const float* __restrict__ WV,
                                               const float* __restrict__ WO,
                                               const float* __restrict__ W1,
                                               const float* __restrict__ W2,
                                               u16* __restrict__ xb,
                                               u16* __restrict__ wqkvb,
                                               u16* __restrict__ wob,
                                               u16* __restrict__ w1b,
                                               u16* __restrict__ w2b) {
  const int S = 1 << 20;
  int i = (blockIdx.x * 256 + threadIdx.x) * 4;
  const float* src;
  u16* dst;
  if (i < 8 * S) { src = x + i; dst = xb + i; }
  else {
    int j = i - 8 * S;
    if (j < 3 * S)      { src = (j < S) ? WQ + j : (j < 2 * S) ? WK + (j - S) : WV + (j - 2 * S);
                          dst = wqkvb + j; }
    else if (j < 4 * S) { src = WO + (j - 3 * S); dst = wob + (j - 3 * S); }
    else if (j < 8 * S) { src = W1 + (j - 4 * S); dst = w1b + (j - 4 * S); }
    else                { src = W2 + (j - 8 * S); dst = w2b + (j - 8 * S); }
  }
  float4 v = *(const float4*)src;
  uint2 o;
  o.x = (u32)f2bf(v.x) | ((u32)f2bf(v.y) << 16);
  o.y = (u32)f2bf(v.z) | ((u32)f2bf(v.w) << 16);
  *(uint2*)dst = o;
}

// ---------------- 256x128 occupancy-oriented bf16 MFMA GEMM: C = A @ W^T + bias ----------------
// 512 threads (8 waves, 4M x 2N), 64x64 per wave (acc = 64 f32), BK=32,
// ring-3 LDS slots (72 KiB), ONE barrier per K-tile, prefetch distance 2 [R7]:
//   {STAGE(t+2) -> slot (t+2)%3; compute(t) from slot t%3; vmcnt(3); barrier}
// Slot (t+2)%3 == (t-1)%3 was read in compute(t-1), which finished before the
// end-of-iter-(t-1) barrier in EVERY wave -> overwrite safe with a single barrier.
// vmcnt(3)+barrier == "tile t+1 staged by ALL waves"; tile t+2's 3 loads stay in
// flight (never drain to 0 in loop) [T4]. Loads get ~2 compute phases to land.
// No explicit lgkmcnt drain: ds_reads are plain loads, compiler emits counted
// lgkmcnt per MFMA operand; all reads feed MFMAs before the barrier, so reads
// are complete at the barrier (ring-3 argument still holds).
// VGPR ~56 arch + 64 acc ~= 120 unified -> 4 waves/SIMD; LDS 72K -> 2 blocks/CU
// (residency was VGPR-capped at 2 blocks anyway, so ring-3 is free) [R6 counters].
// LDS chunk swizzle: phys16B-chunk = logical ^ ((row>>1)&3) on BOTH the
// pre-swizzled global source and the ds_read side (rule #21) -> conflict-free.
// QKV=1: N=3072 fused; seg0 = Q scaled 0.125*log2(e), seg1=K, seg2=V transposed.
// SPLIT=1: K halved, kz=0 -> C0 (+bias), kz=1 -> C1 (bf16 partials). N=1024 fixed.
template <int RELU, int QKV, int SPLIT>
__global__ __launch_bounds__(512, 4) void gemm256(const u16* __restrict__ A,
                                                  const u16* __restrict__ W,
                                                  const float* __restrict__ bias0,
                                                  void* __restrict__ C0,
                                                  int M, int N, int K,
                                                  const float* __restrict__ bias1,
                                                  void* __restrict__ C1,
                                                  const float* __restrict__ bias2,
                                                  void* __restrict__ C2,
                                                  int NBN) {
  __shared__ alignas(16) u16 lds[3 * 12288];  // 3 slots x (A 256x32 + B 128x32) u16 = 72 KiB
  const int tid = threadIdx.x;
  const int id = blockIdx.x;
  const int xcd = id & 7, r = id >> 3;
  int bm, bn, kz = 0, koff = 0, KL = K;
  if (SPLIT) {
    bn = (r & 7) << 7;            // 8 n-tiles of 128 (N = 1024 fixed)
    const int q = r >> 3;         // 0..7
    bm = ((q & 3) * 8 + xcd) << 8;
    kz = q >> 2;
    KL = K >> 1;
    koff = kz * KL;
  } else {
    bn = (r % NBN) << 7;
    bm = ((r / NBN) * 8 + xcd) << 8;
  }
  const int wave = tid >> 6, lane = tid & 63;
  const int lr = lane & 15, quad = lane >> 4;
  const int wm = (wave >> 1) << 6;  // 0,64,128,192
  const int wn = (wave & 1) << 6;   // 0,64

  // staging: one gll16 call = 64 lanes x 16B = 16 rows of 32 u16.
  // wave w: A rows [w*32, w*32+32) (2 calls), B rows [w*16, w*16+16) (1 call).
  // dest lane l -> row l>>2, phys 16B-chunk l&3; source logical chunk = (l&3)^((row>>1)&3).
  const int lrow = lane >> 2;
  const int lch = (lane & 3) ^ ((lane >> 3) & 3);
  const u16* Asrc = A + (size_t)(bm + wave * 32 + lrow) * K + koff + lch * 8;
  const u16* Wsrc = W + (size_t)(bn + wave * 16 + lrow) * K + koff + lch * 8;
  const size_t rK16 = (size_t)16 * K;

  const int NT = KL >> 5;
  const int fro = (quad ^ ((lr >> 1) & 3)) * 8;  // swizzled ds_read chunk offset (u16)
  f32x4 acc[4][4] = {};

#define STAGE(tt, slot) { const int tp_ = ((tt) < NT) ? (tt) : NT - 1;  /* tail: junk, never read */ \
    const size_t ko_ = (size_t)tp_ * 32;                                                             \
    u16* b_ = lds + (slot) * 12288;                                                                  \
    gll16(Asrc + ko_, b_ + wave * 1024);                                                             \
    gll16(Asrc + ko_ + rK16, b_ + wave * 1024 + 512);                                                \
    gll16(Wsrc + ko_, b_ + 8192 + wave * 512); }

  // prologue: tiles 0,1 in flight (slots 0,1); tile 0 landed by all before loop
  STAGE(0, 0);
  STAGE(1, 1);
  waitv3();   // tile 0's 3 loads landed (tile 1's 3 in flight)
  barrier();

  int sc = 0;  // slot of tile t
  for (int t = 0; t < NT; t++) {
    const int ws = (sc == 0) ? 2 : sc - 1;   // (t+2)%3 == (t-1)%3
    STAGE(t + 2, ws);       // 3 loads; in flight across this AND next compute
    const u16* sa = lds + sc * 12288;
    const u16* sb = sa + 8192;
    bf16x8 af[4], bfr[4];
    #pragma unroll
    for (int mi = 0; mi < 4; mi++)
      af[mi] = *(const bf16x8*)(sa + (wm + mi * 16 + lr) * 32 + fro);
    #pragma unroll
    for (int ni = 0; ni < 4; ni++)
      bfr[ni] = *(const bf16x8*)(sb + (wn + ni * 16 + lr) * 32 + fro);
    __builtin_amdgcn_s_setprio(1);
    #pragma unroll
    for (int mi = 0; mi < 4; mi++)
      #pragma unroll
      for (int ni = 0; ni < 4; ni++)
        acc[mi][ni] = __builtin_amdgcn_mfma_f32_16x16x32_bf16(af[mi], bfr[ni], acc[mi][ni], 0, 0, 0);
    __builtin_amdgcn_s_setprio(0);
    waitv3();               // tile t+1 landed by this wave (t+2's 3 outstanding)
    barrier();              // => landed by ALL waves; also: compute(t) reads done
    sc = (sc == 2) ? 0 : sc + 1;
  }
  waitv0();  // drain tail junk loads before LDS dealloc at endpgm
#undef STAGE

  // epilogue: C/D layout col=lane&15, row=quad*4+reg [m89/m91]
  const float* bp = bias0;
  void* outp = C0;
  float scale = 1.0f;
  int cb = bn, Nout = N, seg = 0;
  if (QKV) {
    Nout = 1024;
    seg = bn >> 10;
    cb = bn & 1023;
    if (seg == 0) scale = 0.125f * 1.44269504089f;  // 1/sqrt(dk) * log2(e): attn uses exp2
    else if (seg == 1) { bp = bias1; outp = C1; }
    else { bp = bias2; outp = C2; }
  }
  if (SPLIT && kz) outp = C1;

  if (QKV && seg == 2) {
    // V: store transposed. 4 consecutive tokens per lane -> 8B packed stores.
    #pragma unroll
    for (int ni = 0; ni < 4; ni++) {
      const int col = cb + wn + ni * 16 + lr;
      const int hh = col >> 6, dl = col & 63;
      const float bv = bp[col];
      #pragma unroll
      for (int mi = 0; mi < 4; mi++) {
        const int row0 = bm + wm + mi * 16 + quad * 4;
        const int bb = row0 >> 11, tt = row0 & 2047;
        u16 pk[4];
        #pragma unroll
        for (int rg = 0; rg < 4; rg++) pk[rg] = f2bf(acc[mi][ni][rg] + bv);
        uint2 val;
        val.x = (u32)pk[0] | ((u32)pk[1] << 16);
        val.y = (u32)pk[2] | ((u32)pk[3] << 16);
        *(uint2*)(((u16*)outp) + ((size_t)((bb * 16 + hh) * 64 + dl)) * 2048 + tt) = val;
      }
    }
    return;
  }

  #pragma unroll
  for (int ni = 0; ni < 4; ni++) {
    const int col = cb + wn + ni * 16 + lr;
    const float bv = (SPLIT && kz) ? 0.0f : bp[col];
    #pragma unroll
    for (int mi = 0; mi < 4; mi++) {
      #pragma unroll
      for (int rg = 0; rg < 4; rg++) {
        int row = bm + wm + mi * 16 + quad * 4 + rg;
        float v = (acc[mi][ni][rg] + bv) * scale;
        if (RELU) v = fmaxf(v, 0.0f);
        ((u16*)outp)[(size_t)row * Nout + col] = f2bf(v);
      }
    }
  }
}

// ---------------- MFMA flash attention: 32x32, TLP-oriented grid [R4 post-mortem] ----------------
// One 64-query q-tile per block, 2048 blocks (b,h,p) longest-first (p = 31 - i>>6);
// same-bh blocks share an XCD (i&7 = bh&7) for K/V L2 reuse. 4 waves = 2 q-subtiles
// x 2-way k-split (wave>>1 = parity of k-tiles): every wave computes every iter,
// sweep halves (<=16 iters), partials combined through LDS at the end (no HBM).
// Single-buffered staging {barrier; stage 2 tiles; vmcnt(0); barrier; compute}:
// exposed latency is hidden by ~5 co-resident blocks/CU (TLP, m169), not pipelining.
// S^T = K Q^T via mfma_32x32x16(kf, qf): D col=lane&31=query, row=(reg&3)+8*(reg>>2)+4*(lane>>5)=key
// [m74/m101]. Softmax fully in-register (exp2, Q pre-scaled log2(e)/8); truncated-bf16
// v_perm packs + one v_permlane32_swap per word-pair build the PV A-fragment.
__global__ __launch_bounds__(256) void attn_mfma(const u16* __restrict__ qb,
                                                 const u16* __restrict__ kb,
                                                 const u16* __restrict__ vt,
                                                 u16* __restrict__ ctxb, int T) {
  __shared__ alignas(16) u16 shm[4 * 4096];  // [K even][K odd][V even][V odd], 8 KiB each
  const int tid = threadIdx.x;
  const int i = blockIdx.x;
  const int g = i & 63;                      // bh index; i&7 = XCD -> all p of a bh colocated
  const int p = 31 - (i >> 6);               // longest blocks dispatched first
  const int h = g >> 2, b = g & 3;
  const size_t base = ((size_t)(b * T)) * 1024 + h * 64;
  const size_t vbase = ((size_t)((b * 16 + h) * 64)) * T;
  const int lane = tid & 63, wave = tid >> 6;
  const int l31 = lane & 31, hh = lane >> 5;
  const int sub = wave & 1;                  // q-subtile (32 q)
  const int kh = wave >> 1;                  // k-parity handled by this wave
  const int srow = lane >> 3;
  const int sch = ((lane & 7) ^ srow) * 8;
  const int fs8 = l31 & 7;
  const int q0w = p * 64 + sub * 32;

  // Q fragments (B-operand): lane holds Q[q0w+l31][ds*16 + hh*8 + 0..7]
  bf16x8 qf[4];
  #pragma unroll
  for (int ds = 0; ds < 4; ds++) {
    uint4 uq = *(const uint4*)(qb + base + (size_t)(q0w + l31) * 1024 + ds * 16 + hh * 8);
    qf[ds] = __builtin_bit_cast(bf16x8, uq);
  }
  f32x16 o0 = {}, o1 = {};
  float rsum = 0.0f;

  const int NI = (p >> 1) + 1;               // iters; iter j covers k-tiles 2j, 2j+1
  for (int j = 0; j < NI; j++) {
    const int ke = 2 * j;                    // always <= p
    const int ko = (2 * j + 1 <= p) ? 2 * j + 1 : p;  // clamp (clamped tile never computed)
    barrier();                               // prev iter's reads of shm done
    #pragma unroll
    for (int jj = 0; jj < 2; jj++) {
      const int rb = wave * 16 + jj * 8;
      const int rr = rb + srow;
      gll16(kb + base + (size_t)(ke * 64 + rr) * 1024 + sch, shm + rb * 64);
      gll16(kb + base + (size_t)(ko * 64 + rr) * 1024 + sch, shm + 4096 + rb * 64);
      gll16(vt + vbase + (size_t)rr * T + (size_t)(ke * 64) + sch, shm + 8192 + rb * 64);
      gll16(vt + vbase + (size_t)rr * T + (size_t)(ko * 64) + sch, shm + 12288 + rb * 64);
    }
    waitv0();
    barrier();                               // all waves' tiles staged
    const int kt = 2 * j + kh;
    if (kt <= p) {
      const u16* sKc = shm + kh * 4096;
      const u16* sVc = shm + 8192 + kh * 4096;

      // S^T = K Q^T: s0 = keys kt*64+0..31, s1 = +32..63 (row-split by hh)
      f32x16 s0v = {}, s1v = {};
      #pragma unroll
      for (int ds = 0; ds < 4; ds++) {
        const int co = ((2 * ds + hh) ^ fs8) * 8;
        bf16x8 kf0 = *(const bf16x8*)(sKc + l31 * 64 + co);
        bf16x8 kf1 = *(const bf16x8*)(sKc + (32 + l31) * 64 + co);
        s0v = __builtin_amdgcn_mfma_f32_32x32x16_bf16(kf0, qf[ds], s0v, 0, 0, 0);
        s1v = __builtin_amdgcn_mfma_f32_32x32x16_bf16(kf1, qf[ds], s1v, 0, 0, 0);
      }

      // causal mask on the diagonal tile
      if (kt == p) {
        const int qloc = (sub << 5) + l31;
        #pragma unroll
        for (int rg = 0; rg < 16; rg++) {
          const int key = (rg & 3) + 8 * (rg >> 2) + 4 * hh;
          if (key > qloc) s0v[rg] = -1e30f;
          if (key + 32 > qloc) s1v[rg] = -1e30f;
        }
      }

      // P = exp2(S) in-register; row-sum per lane (its own query)
      float e[32];
      #pragma unroll
      for (int rg = 0; rg < 16; rg++) {
        e[rg] = __builtin_amdgcn_exp2f(s0v[rg]);
        e[16 + rg] = __builtin_amdgcn_exp2f(s1v[rg]);
        rsum += e[rg] + e[16 + rg];
      }

      // pack to PV A-fragments: pf[s] = P[q=l31][keys 16s + hh*8 + 0..7]
      union PW { u32 w[4]; bf16x8 v; } pf[4];
      #pragma unroll
      for (int t = 0; t < 2; t++) {
        #pragma unroll
        for (int sl = 0; sl < 2; sl++) {
          const int rb = t * 16 + sl * 8;
          u32 wa = __builtin_amdgcn_perm(__builtin_bit_cast(u32, e[rb + 1]), __builtin_bit_cast(u32, e[rb + 0]), 0x07060302u);
          u32 wb = __builtin_amdgcn_perm(__builtin_bit_cast(u32, e[rb + 5]), __builtin_bit_cast(u32, e[rb + 4]), 0x07060302u);
          u32 wc = __builtin_amdgcn_perm(__builtin_bit_cast(u32, e[rb + 3]), __builtin_bit_cast(u32, e[rb + 2]), 0x07060302u);
          u32 wd = __builtin_amdgcn_perm(__builtin_bit_cast(u32, e[rb + 7]), __builtin_bit_cast(u32, e[rb + 6]), 0x07060302u);
          asm("v_permlane32_swap_b32 %0, %1" : "+v"(wa), "+v"(wb));
          asm("v_permlane32_swap_b32 %0, %1" : "+v"(wc), "+v"(wd));
          pf[t * 2 + sl].w[0] = wa; pf[t * 2 + sl].w[1] = wc;
          pf[t * 2 + sl].w[2] = wb; pf[t * 2 + sl].w[3] = wd;
        }
      }

      // O += P V : vf (B-operand) from V^T LDS; o0 = d 0..31, o1 = d 32..63
      #pragma unroll
      for (int s = 0; s < 4; s++) {
        const int co = ((2 * s + hh) ^ fs8) * 8;
        bf16x8 vf0 = *(const bf16x8*)(sVc + l31 * 64 + co);
        bf16x8 vf1 = *(const bf16x8*)(sVc + (32 + l31) * 64 + co);
        o0 = __builtin_amdgcn_mfma_f32_32x32x16_bf16(pf[s].v, vf0, o0, 0, 0, 0);
        o1 = __builtin_amdgcn_mfma_f32_32x32x16_bf16(pf[s].v, vf1, o1, 0, 0, 0);
      }
    }
  }

  // combine k-parity partials through LDS (shm no longer needed for staging)
  rsum += __shfl_xor(rsum, 32);   // combine hh halves: full partial sum for query l31
  barrier();                      // all waves done reading shm
  float* red = (float*)shm;       // 2 subtiles x (32 o-regs + 1 rsum) x 64 lanes = 4224 f32
  if (kh == 1) {
    #pragma unroll
    for (int rg = 0; rg < 16; rg++) {
      red[sub * 2112 + rg * 64 + lane] = o0[rg];
      red[sub * 2112 + (16 + rg) * 64 + lane] = o1[rg];
    }
    red[sub * 2112 + 2048 + lane] = rsum;
  }
  barrier();
  if (kh == 0) {
    #pragma unroll
    for (int rg = 0; rg < 16; rg++) {
      o0[rg] += red[sub * 2112 + rg * 64 + lane];
      o1[rg] += red[sub * 2112 + (16 + rg) * 64 + lane];
    }
    rsum += red[sub * 2112 + 2048 + lane];
    float inv = 1.0f / rsum;      // valid at lane == its query (both halves)
    #pragma unroll
    for (int rg = 0; rg < 16; rg++) {
      const int qr = (rg & 3) + 8 * (rg >> 2) + 4 * hh;  // local q-row of this reg
      float iv = __shfl(inv, qr);
      const size_t rowoff = base + (size_t)(q0w + qr) * 1024;
      ctxb[rowoff + l31] = f2bf(o0[rg] * iv);
      ctxb[rowoff + 32 + l31] = f2bf(o1[rg] * iv);
    }
  }
}

// ---------------- fused residual + split-K reduce (bf16 partials) + LayerNorm ----------------
// out = LN(a + b + c) * g + be ;  a is fp32 (ABF=0) or bf16 (ABF=1); b,c bf16 partials
template <int ABF>
__global__ __launch_bounds__(256) void ln_kernel(const void* __restrict__ a,
                                                 const u16* __restrict__ b,
                                                 const u16* __restrict__ c,
                                                 const float* __restrict__ g,
                                                 const float* __restrict__ be,
                                                 float* __restrict__ of32,
                                                 u16* __restrict__ obf) {
  const int row = blockIdx.x;
  const int tid = threadIdx.x;
  const size_t base = (size_t)row * 1024;
  const int cc = tid * 4;
  float a0, a1, a2, a3;
  if (ABF) {
    uint2 ua = *(const uint2*)((const u16*)a + base + cc);
    a0 = bf2f(ua.x & 0xffff); a1 = bf2f(ua.x >> 16);
    a2 = bf2f(ua.y & 0xffff); a3 = bf2f(ua.y >> 16);
  } else {
    float4 xa = *(const float4*)((const float*)a + base + cc);
    a0 = xa.x; a1 = xa.y; a2 = xa.z; a3 = xa.w;
  }
  uint2 ub = *(const uint2*)(b + base + cc);
  uint2 uc = *(const uint2*)(c + base + cc);
  float v0 = a0 + bf2f(ub.x & 0xffff) + bf2f(uc.x & 0xffff);
  float v1 = a1 + bf2f(ub.x >> 16)    + bf2f(uc.x >> 16);
  float v2 = a2 + bf2f(ub.y & 0xffff) + bf2f(uc.y & 0xffff);
  float v3 = a3 + bf2f(ub.y >> 16)    + bf2f(uc.y >> 16);
  float s1 = v0 + v1 + v2 + v3;
  float s2 = v0 * v0 + v1 * v1 + v2 * v2 + v3 * v3;
  for (int off = 1; off < 64; off <<= 1) {
    s1 += __shfl_xor(s1, off);
    s2 += __shfl_xor(s2, off);
  }
  __shared__ float red[8];
  int wv = tid >> 6;
  if ((tid & 63) == 0) { red[wv] = s1; red[4 + wv] = s2; }
  __syncthreads();
  s1 = red[0] + red[1] + red[2] + red[3];
  s2 = red[4] + red[5] + red[6] + red[7];
  float mu = s1 * (1.0f / 1024.0f);
  float var = s2 * (1.0f / 1024.0f) - mu * mu;
  float rs = rsqrtf(var + 1e-5f);
  float4 gv = *(const float4*)(g + cc);
  float4 bev = *(const float4*)(be + cc);
  float y0 = (v0 - mu) * rs * gv.x + bev.x;
  float y1 = (v1 - mu) * rs * gv.y + bev.y;
  float y2 = (v2 - mu) * rs * gv.z + bev.z;
  float y3 = (v3 - mu) * rs * gv.w + bev.w;
  if (of32) {
    float4 o = make_float4(y0, y1, y2, y3);
    *(float4*)(of32 + base + cc) = o;
  }
  if (obf) {
    uint2 o;
    o.x = (u32)f2bf(y0) | ((u32)f2bf(y1) << 16);
    o.y = (u32)f2bf(y2) | ((u32)f2bf(y3) << 16);
    *(uint2*)(obf + base + cc) = o;
  }
}

// ---------------- launch ----------------
extern "C" void kernel_launch(void* const* d_in, const int* in_sizes, int n_in,
                              void* d_out, int out_size, void* d_ws, size_t ws_size,
                              hipStream_t stream) {
  const int Mtok = 8192, D = 1024, F = 4096, T = 2048;
  const float* x   = (const float*)d_in[0];
  const float* WQ  = (const float*)d_in[1];
  const float* bQ  = (const float*)d_in[2];
  const float* WK  = (const float*)d_in[3];
  const float* bK  = (const float*)d_in[4];
  const float* WV  = (const float*)d_in[5];
  const float* bV  = (const float*)d_in[6];
  const float* WO  = (const float*)d_in[7];
  const float* bO  = (const float*)d_in[8];
  const float* W1  = (const float*)d_in[9];
  const float* b1  = (const float*)d_in[10];
  const float* W2  = (const float*)d_in[11];
  const float* b2  = (const float*)d_in[12];
  const float* g1  = (const float*)d_in[13];
  const float* be1 = (const float*)d_in[14];
  const float* g2  = (const float*)d_in[15];
  const float* be2 = (const float*)d_in[16];

  char* ws = (char*)d_ws;
  const size_t MB = 1024 * 1024;
  u16*  xb     = (u16*)(ws + 0);          // 16 MB (dead after QKV)
  u16*  wqkvb  = (u16*)(ws + 16 * MB);    // 6 MB  (dead after QKV)
  u16*  wob    = (u16*)(ws + 22 * MB);    // 2 MB  (dead after WO)
  u16*  w1b    = (u16*)(ws + 24 * MB);    // 8 MB  (dead after FF1)
  u16*  w2b    = (u16*)(ws + 32 * MB);    // 8 MB  (dead after FF2)
  u16*  qb     = (u16*)(ws + 40 * MB);    // 16 MB (dead after attn)
  u16*  kb     = (u16*)(ws + 56 * MB);    // 16 MB (dead after attn)
  u16*  vtb    = (u16*)(ws + 72 * MB);    // 16 MB, written transposed by QKV (dead after attn)
  u16*  ctxb   = (u16*)(ws + 88 * MB);    // 16 MB (dead after WO)
  u16*  wp0    = (u16*)(ws + 104 * MB);   // 16 MB bf16 partial (dead after ln1)
  u16*  wp1    = (u16*)(ws + 120 * MB);   // 16 MB bf16 partial (dead after ln1)
  u16*  h1b    = (u16*)(ws + 136 * MB);   // 16 MB bf16 LN1 output (live until ln2)
  u16*  ff1b   = (u16*)(ws + 40 * MB);    // 64 MB over qb..ctxb (dead after FF2)
  u16*  fp0    = (u16*)(ws + 0);          // 16 MB bf16 partial over xb
  u16*  fp1    = (u16*)(ws + 16 * MB);    // 16 MB bf16 partial over wqkvb/wob
  float* out   = (float*)d_out;

  dim3 blk(256);
  dim3 blk512(512);
  cvt_all<<<(20 << 20) / 1024, blk, 0, stream>>>(x, WQ, WK, WV, WO, W1, W2,
                                                 xb, wqkvb, wob, w1b, w2b);

  // fused QKV (N=3072): seg0=Q scaled log2(e)/8, seg1=K, seg2=V stored transposed
  gemm256<0, 1, 0><<<dim3(768), blk512, 0, stream>>>(xb, wqkvb, bQ, qb, Mtok, 3072, D,
                                                     bK, kb, bV, vtb, 24);
  attn_mfma<<<dim3(2048), blk, 0, stream>>>(qb, kb, vtb, ctxb, T);

  // WO projection, split-K=2 -> bf16 partials wp0/wp1; ln1 reduces
  gemm256<0, 0, 1><<<dim3(512), blk512, 0, stream>>>(ctxb, wob, bO, wp0, Mtok, D, D,
                                                     nullptr, wp1, nullptr, nullptr, 8);
  ln_kernel<0><<<Mtok, blk, 0, stream>>>(x, wp0, wp1, g1, be1, nullptr, h1b);

  gemm256<1, 0, 0><<<dim3(1024), blk512, 0, stream>>>(h1b, w1b, b1, ff1b, Mtok, F, D,
                                                      nullptr, nullptr, nullptr, nullptr, 32);
  // FF2, split-K=2 -> bf16 partials fp0/fp1; ln2 reduces (bf16 residual h1b)
  gemm256<0, 0, 1><<<dim3(512), blk512, 0, stream>>>(ff1b, w2b, b2, fp0, Mtok, D, F,
                                                     nullptr, fp1, nullptr, nullptr, 8);
  ln_kernel<1><<<Mtok, blk, 0, stream>>>(h1b, fp0, fp1, g2, be2, out, (u16*)nullptr);
}

// Round 10
// 457.187 us; speedup vs baseline: 1.0113x; 1.0113x over previous
//
#include <hip/hip_runtime.h>

typedef unsigned short u16;
typedef unsigned int u32;
typedef __bf16 bf16x8 __attribute__((ext_vector_type(8)));
typedef float f32x4 __attribute__((ext_vector_type(4)));
typedef float f32x16 __attribute__((ext_vector_type(16)));

__device__ __forceinline__ u16 f2bf(float f) {
  u32 u = __builtin_bit_cast(u32, f);
  u = (u + 0x7fffu + ((u >> 16) & 1u)) >> 16;
  return (u16)u;
}
__device__ __forceinline__ float bf2f(u16 h) {
  return __builtin_bit_cast(float, ((u32)h) << 16);
}

// async global->LDS, 16B per lane; LDS dest = wave-uniform base + lane*16 [m97/m104]
__device__ __forceinline__ void gll16(const u16* g, u16* l) {
  __builtin_amdgcn_global_load_lds((const __attribute__((address_space(1))) void*)g,
                                   (__attribute__((address_space(3))) void*)l, 16, 0, 0);
}

// raw barrier: NO implicit vmcnt drain (the whole point of the counted pipeline)
__device__ __forceinline__ void barrier() {
  asm volatile("" ::: "memory");
  __builtin_amdgcn_s_barrier();
  asm volatile("" ::: "memory");
}
__device__ __forceinline__ void waitv4() { asm volatile("s_waitcnt vmcnt(4)" ::: "memory"); }
__device__ __forceinline__ void waitv3() { asm volatile("s_waitcnt vmcnt(3)" ::: "memory"); }
__device__ __forceinline__ void waitv0() { asm volatile("s_waitcnt vmcnt(0)" ::: "memory"); }

// ---------------- all fp32 -> bf16 conversions in one launch ----------------
__global__ __launch_bounds__(256) void cvt_all(const float* __restrict__ x,
                                               const float* __restrict__ WQ,
                                               const float* __restrict__ WK,
                                               const float* __restrict__ WV,
                                               const float* __restrict__ WO,
                                               const float* __restrict__ W1,
                                               const float* __restrict__ W2,
                                               u16* __restrict__ xb,
                                               u16* __restrict__ wqkvb,
                                               u16* __restrict__ wob,
                                               u16* __restrict__ w1b,
                                               u16* __restrict__ w2b) {
  const int S = 1 << 20;
  int i = (blockIdx.x * 256 + threadIdx.x) * 4;
  const float* src;
  u16* dst;
  if (i < 8 * S) { src = x + i; dst = xb + i; }
  else {
    int j = i - 8 * S;
    if (j < 3 * S)      { src = (j < S) ? WQ + j : (j < 2 * S) ? WK + (j - S) : WV + (j - 2 * S);
                          dst = wqkvb + j; }
    else if (j < 4 * S) { src = WO + (j - 3 * S); dst = wob + (j - 3 * S); }
    else if (j < 8 * S) { src = W1 + (j - 4 * S); dst = w1b + (j - 4 * S); }
    else                { src = W2 + (j - 8 * S); dst = w2b + (j - 8 * S); }
  }
  float4 v = *(const float4*)src;
  uint2 o;
  o.x = (u32)f2bf(v.x) | ((u32)f2bf(v.y) << 16);
  o.y = (u32)f2bf(v.z) | ((u32)f2bf(v.w) << 16);
  *(uint2*)dst = o;
}

// ---------------- 256x128 occupancy-oriented bf16 MFMA GEMM: C = A @ W^T + bias ----------------
// [R6-proven version: 78.5 us FF1, MfmaUtil 37%, occupancy 37%. R8's ring-3 regressed -> reverted.]
// 512 threads (8 waves, 4M x 2N), 64x64 per wave (acc = 64 f32), BK=32,
// ring-2 LDS slots (48 KiB) -> 2 blocks/CU resident; __launch_bounds__(512,4)
// caps VGPR at 128 so occupancy is 4 waves/SIMD. Cross-block TLP hides the
// staging/barrier stalls [R5 post-mortem; m114/m97 mechanism].
// Counted vmcnt [T4]: stage(t+1) at top of iter (3 loads/wave: 2xA, 1xB),
// vmcnt(3) == "tile t landed by this wave" + barrier == landed by ALL waves;
// tile t+1's loads stay in flight across the compute (never drain to 0 in loop).
// LDS chunk swizzle: phys16B-chunk = logical ^ ((row>>1)&3) on BOTH the
// pre-swizzled global source and the ds_read side (rule #21) -> conflict-free.
// QKV=1: N=3072 fused; seg0 = Q scaled 0.125*log2(e), seg1=K, seg2=V transposed.
// SPLIT=1: K halved, kz=0 -> C0 (+bias), kz=1 -> C1 (bf16 partials). N=1024 fixed.
template <int RELU, int QKV, int SPLIT>
__global__ __launch_bounds__(512, 4) void gemm256(const u16* __restrict__ A,
                                                  const u16* __restrict__ W,
                                                  const float* __restrict__ bias0,
                                                  void* __restrict__ C0,
                                                  int M, int N, int K,
                                                  const float* __restrict__ bias1,
                                                  void* __restrict__ C1,
                                                  const float* __restrict__ bias2,
                                                  void* __restrict__ C2,
                                                  int NBN) {
  __shared__ alignas(16) u16 lds[2 * 12288];  // 2 slots x (A 256x32 + B 128x32) u16 = 48 KiB
  const int tid = threadIdx.x;
  const int id = blockIdx.x;
  const int xcd = id & 7, r = id >> 3;
  int bm, bn, kz = 0, koff = 0, KL = K;
  if (SPLIT) {
    bn = (r & 7) << 7;            // 8 n-tiles of 128 (N = 1024 fixed)
    const int q = r >> 3;         // 0..7
    bm = ((q & 3) * 8 + xcd) << 8;
    kz = q >> 2;
    KL = K >> 1;
    koff = kz * KL;
  } else {
    bn = (r % NBN) << 7;
    bm = ((r / NBN) * 8 + xcd) << 8;
  }
  const int wave = tid >> 6, lane = tid & 63;
  const int lr = lane & 15, quad = lane >> 4;
  const int wm = (wave >> 1) << 6;  // 0,64,128,192
  const int wn = (wave & 1) << 6;   // 0,64

  // staging: one gll16 call = 64 lanes x 16B = 16 rows of 32 u16.
  // wave w: A rows [w*32, w*32+32) (2 calls), B rows [w*16, w*16+16) (1 call).
  // dest lane l -> row l>>2, phys 16B-chunk l&3; source logical chunk = (l&3)^((row>>1)&3).
  const int lrow = lane >> 2;
  const int lch = (lane & 3) ^ ((lane >> 3) & 3);
  const u16* Asrc = A + (size_t)(bm + wave * 32 + lrow) * K + koff + lch * 8;
  const u16* Wsrc = W + (size_t)(bn + wave * 16 + lrow) * K + koff + lch * 8;
  const size_t rK16 = (size_t)16 * K;

  const int NT = KL >> 5;
  const int fro = (quad ^ ((lr >> 1) & 3)) * 8;  // swizzled ds_read chunk offset (u16)
  f32x4 acc[4][4] = {};

#define STAGE(tt) { const int tp_ = ((tt) < NT) ? (tt) : NT - 1;   /* tail: junk slot never read */ \
    const size_t ko_ = (size_t)tp_ * 32;                                                            \
    u16* b_ = lds + ((tt) & 1) * 12288;                                                             \
    gll16(Asrc + ko_, b_ + wave * 1024);                                                            \
    gll16(Asrc + ko_ + rK16, b_ + wave * 1024 + 512);                                               \
    gll16(Wsrc + ko_, b_ + 8192 + wave * 512); }

  STAGE(0);  // prologue: tile 0 in flight (3 loads/wave)

  for (int t = 0; t < NT; t++) {
    barrier();              // all waves done reading slot (t+1)&1 (iter t-1's compute)
    STAGE(t + 1);           // prefetch next tile; stays in flight across compute
    waitv3();               // this wave's tile-t loads landed
    barrier();              // => ALL waves' tile-t loads landed
    const u16* sa = lds + (t & 1) * 12288;
    const u16* sb = sa + 8192;
    bf16x8 af[4], bfr[4];
    #pragma unroll
    for (int mi = 0; mi < 4; mi++)
      af[mi] = *(const bf16x8*)(sa + (wm + mi * 16 + lr) * 32 + fro);
    #pragma unroll
    for (int ni = 0; ni < 4; ni++)
      bfr[ni] = *(const bf16x8*)(sb + (wn + ni * 16 + lr) * 32 + fro);
    asm volatile("s_waitcnt lgkmcnt(0)" ::: "memory");
    __builtin_amdgcn_s_setprio(1);
    #pragma unroll
    for (int mi = 0; mi < 4; mi++)
      #pragma unroll
      for (int ni = 0; ni < 4; ni++)
        acc[mi][ni] = __builtin_amdgcn_mfma_f32_16x16x32_bf16(af[mi], bfr[ni], acc[mi][ni], 0, 0, 0);
    __builtin_amdgcn_s_setprio(0);
  }
  waitv0();  // drain tail junk loads before LDS dealloc at endpgm
#undef STAGE

  // epilogue: C/D layout col=lane&15, row=quad*4+reg [m89/m91]
  const float* bp = bias0;
  void* outp = C0;
  float scale = 1.0f;
  int cb = bn, Nout = N, seg = 0;
  if (QKV) {
    Nout = 1024;
    seg = bn >> 10;
    cb = bn & 1023;
    if (seg == 0) scale = 0.125f * 1.44269504089f;  // 1/sqrt(dk) * log2(e): attn uses exp2
    else if (seg == 1) { bp = bias1; outp = C1; }
    else { bp = bias2; outp = C2; }
  }
  if (SPLIT && kz) outp = C1;

  if (QKV && seg == 2) {
    // V: store transposed. 4 consecutive tokens per lane -> 8B packed stores.
    #pragma unroll
    for (int ni = 0; ni < 4; ni++) {
      const int col = cb + wn + ni * 16 + lr;
      const int hh = col >> 6, dl = col & 63;
      const float bv = bp[col];
      #pragma unroll
      for (int mi = 0; mi < 4; mi++) {
        const int row0 = bm + wm + mi * 16 + quad * 4;
        const int bb = row0 >> 11, tt = row0 & 2047;
        u16 pk[4];
        #pragma unroll
        for (int rg = 0; rg < 4; rg++) pk[rg] = f2bf(acc[mi][ni][rg] + bv);
        uint2 val;
        val.x = (u32)pk[0] | ((u32)pk[1] << 16);
        val.y = (u32)pk[2] | ((u32)pk[3] << 16);
        *(uint2*)(((u16*)outp) + ((size_t)((bb * 16 + hh) * 64 + dl)) * 2048 + tt) = val;
      }
    }
    return;
  }

  #pragma unroll
  for (int ni = 0; ni < 4; ni++) {
    const int col = cb + wn + ni * 16 + lr;
    const float bv = (SPLIT && kz) ? 0.0f : bp[col];
    #pragma unroll
    for (int mi = 0; mi < 4; mi++) {
      #pragma unroll
      for (int rg = 0; rg < 4; rg++) {
        int row = bm + wm + mi * 16 + quad * 4 + rg;
        float v = (acc[mi][ni][rg] + bv) * scale;
        if (RELU) v = fmaxf(v, 0.0f);
        ((u16*)outp)[(size_t)row * Nout + col] = f2bf(v);
      }
    }
  }
}

// ---------------- MFMA flash attention: 128q blocks + counted-vmcnt ring-2 [R10] ----------------
// One 128-query tile per block (4 waves x 32q, no k-split, no LDS reduce), 1024 blocks
// (b,h,qb) longest-first (qb = 15 - i>>6); same-bh blocks share an XCD (i&7 = bh&7).
// Staging traffic HALVES vs the 64q version (each K/V k-tile staged once per 128q).
// K/V ring-2 (32 KiB) with counted vmcnt [T3/T4, proven in gemm]: per iter
// {barrier; STAGE(kt+1)->slot (kt+1)&1; vmcnt(4); barrier; compute(kt)} — each wave
// stages its own 4 loads, so vmcnt(4)+barrier == tile kt staged by ALL waves; kt+1's
// loads stay in flight across the whole compute. ~4 blocks/CU resident -> all 1024
// blocks co-resident (no tail rounds) + TLP hides residual latency [m169].
// R9 BUG FIX: wave q-blocks are 32-aligned but k-tiles 64-wide, so for odd waves the
// diagonal tile is kq = q0w-32 with kq+63 == q0w+31; the old gate (kq+63 > q0w+31)
// skipped masking there -> causal leak (absmax 0.227). Gate on the MIN query:
// mask whenever kq+63 > q0w (per-lane compares handle the rest; exp2(-1e30)=0).
// S^T = K Q^T via mfma_32x32x16(kf, qf): D col=lane&31=query, row=(reg&3)+8*(reg>>2)+4*(lane>>5)=key
// [m74/m101]. Softmax fully in-register (exp2, Q pre-scaled log2(e)/8); truncated-bf16
// v_perm packs + one v_permlane32_swap per word-pair build the PV A-fragment.
__global__ __launch_bounds__(256) void attn_mfma(const u16* __restrict__ qb,
                                                 const u16* __restrict__ kb,
                                                 const u16* __restrict__ vt,
                                                 u16* __restrict__ ctxb, int T) {
  __shared__ alignas(16) u16 shm[2][8192];   // slot = K 64x64 (8KB) + V^T 64x64 (8KB)
  const int tid = threadIdx.x;
  const int i = blockIdx.x;
  const int g = i & 63;                      // bh index; i&7 = g&7 = XCD -> bh colocated
  const int qb0 = 15 - (i >> 6);             // longest blocks dispatched first
  const int h = g >> 2, b = g & 3;
  const size_t base = ((size_t)(b * T)) * 1024 + h * 64;
  const size_t vbase = ((size_t)((b * 16 + h) * 64)) * T;
  const int lane = tid & 63, wave = tid >> 6;
  const int l31 = lane & 31, hh = lane >> 5;
  const int srow = lane >> 3;
  const int sch = ((lane & 7) ^ srow) * 8;
  const int fs8 = l31 & 7;
  const int q0w = qb0 * 128 + wave * 32;     // this wave's 32-query block (global row)
  const int NK = 2 * qb0 + 2;                // k-tiles needed by the block's 128 queries

  // stage tile ktt's K/V into slot; clamp past-end source (junk slot never read).
  // 4 gll16/wave (2 K + 2 V), block-cooperative: wave w covers rows w*16..w*16+15.
#define STAGEKV(ktt, slot) {                                                        \
    const int kc_ = ((ktt) < NK) ? (ktt) : NK - 1;                                  \
    _Pragma("unroll") for (int j_ = 0; j_ < 2; j_++) {                              \
      const int rb_ = wave * 16 + j_ * 8;                                           \
      const int rr_ = rb_ + srow;                                                   \
      gll16(kb + base + (size_t)(kc_ * 64 + rr_) * 1024 + sch, shm[slot] + rb_ * 64);\
      gll16(vt + vbase + (size_t)rr_ * T + (size_t)(kc_ * 64) + sch, shm[slot] + 4096 + rb_ * 64);\
    } }

  // Q fragments (B-operand): lane holds Q[q0w+l31][ds*16 + hh*8 + 0..7]
  bf16x8 qf[4];
  #pragma unroll
  for (int ds = 0; ds < 4; ds++) {
    uint4 uq = *(const uint4*)(qb + base + (size_t)(q0w + l31) * 1024 + ds * 16 + hh * 8);
    qf[ds] = __builtin_bit_cast(bf16x8, uq);
  }
  f32x16 o0 = {}, o1 = {};
  float rsum = 0.0f;

  STAGEKV(0, 0);  // prologue: tile 0 in flight (4 loads/wave)

  for (int kt = 0; kt < NK; kt++) {
    barrier();                      // all waves done reading slot (kt+1)&1 (iter kt-1)
    STAGEKV(kt + 1, (kt + 1) & 1);  // prefetch next tile; stays in flight across compute
    waitv4();                       // this wave's tile-kt loads landed
    barrier();                      // => ALL waves' tile-kt loads landed
    const int kq = kt * 64;         // first key of this tile
    if (kq <= q0w + 31) {           // tile intersects this wave's causal range
      const u16* sKc = shm[kt & 1];
      const u16* sVc = shm[kt & 1] + 4096;

      // S^T = K Q^T: s0 = keys kq+0..31, s1 = kq+32..63 (row-split by hh)
      f32x16 s0v = {}, s1v = {};
      #pragma unroll
      for (int ds = 0; ds < 4; ds++) {
        const int co = ((2 * ds + hh) ^ fs8) * 8;
        bf16x8 kf0 = *(const bf16x8*)(sKc + l31 * 64 + co);
        bf16x8 kf1 = *(const bf16x8*)(sKc + (32 + l31) * 64 + co);
        s0v = __builtin_amdgcn_mfma_f32_32x32x16_bf16(kf0, qf[ds], s0v, 0, 0, 0);
        s1v = __builtin_amdgcn_mfma_f32_32x32x16_bf16(kf1, qf[ds], s1v, 0, 0, 0);
      }

      // causal mask: needed whenever the tile contains keys beyond the wave's
      // MIN query (q0w) — includes odd waves' straddling tile kq = q0w-32 [R9 fix]
      if (kq + 63 > q0w) {
        const int qg = q0w + l31;
        #pragma unroll
        for (int rg = 0; rg < 16; rg++) {
          const int key = kq + (rg & 3) + 8 * (rg >> 2) + 4 * hh;
          if (key > qg) s0v[rg] = -1e30f;
          if (key + 32 > qg) s1v[rg] = -1e30f;
        }
      }

      // P = exp2(S) in-register; row-sum per lane (its own query)
      float e[32];
      #pragma unroll
      for (int rg = 0; rg < 16; rg++) {
        e[rg] = __builtin_amdgcn_exp2f(s0v[rg]);
        e[16 + rg] = __builtin_amdgcn_exp2f(s1v[rg]);
        rsum += e[rg] + e[16 + rg];
      }

      // pack to PV A-fragments: pf[s] = P[q=l31][keys 16s + hh*8 + 0..7]
      union PW { u32 w[4]; bf16x8 v; } pf[4];
      #pragma unroll
      for (int t = 0; t < 2; t++) {
        #pragma unroll
        for (int sl = 0; sl < 2; sl++) {
          const int rb = t * 16 + sl * 8;
          u32 wa = __builtin_amdgcn_perm(__builtin_bit_cast(u32, e[rb + 1]), __builtin_bit_cast(u32, e[rb + 0]), 0x07060302u);
          u32 wb = __builtin_amdgcn_perm(__builtin_bit_cast(u32, e[rb + 5]), __builtin_bit_cast(u32, e[rb + 4]), 0x07060302u);
          u32 wc = __builtin_amdgcn_perm(__builtin_bit_cast(u32, e[rb + 3]), __builtin_bit_cast(u32, e[rb + 2]), 0x07060302u);
          u32 wd = __builtin_amdgcn_perm(__builtin_bit_cast(u32, e[rb + 7]), __builtin_bit_cast(u32, e[rb + 6]), 0x07060302u);
          asm("v_permlane32_swap_b32 %0, %1" : "+v"(wa), "+v"(wb));
          asm("v_permlane32_swap_b32 %0, %1" : "+v"(wc), "+v"(wd));
          pf[t * 2 + sl].w[0] = wa; pf[t * 2 + sl].w[1] = wc;
          pf[t * 2 + sl].w[2] = wb; pf[t * 2 + sl].w[3] = wd;
        }
      }

      // O += P V : vf (B-operand) from V^T LDS; o0 = d 0..31, o1 = d 32..63
      #pragma unroll
      for (int s = 0; s < 4; s++) {
        const int co = ((2 * s + hh) ^ fs8) * 8;
        bf16x8 vf0 = *(const bf16x8*)(sVc + l31 * 64 + co);
        bf16x8 vf1 = *(const bf16x8*)(sVc + (32 + l31) * 64 + co);
        o0 = __builtin_amdgcn_mfma_f32_32x32x16_bf16(pf[s].v, vf0, o0, 0, 0, 0);
        o1 = __builtin_amdgcn_mfma_f32_32x32x16_bf16(pf[s].v, vf1, o1, 0, 0, 0);
      }
    }
  }
  waitv0();  // drain tail junk loads before LDS dealloc at endpgm
#undef STAGEKV

  // epilogue: direct write (wave owns its 32 queries completely; no cross-wave reduce)
  rsum += __shfl_xor(rsum, 32);   // combine hh halves: full sum for query l31
  float inv = 1.0f / rsum;        // valid at lane == its query (both halves)
  #pragma unroll
  for (int rg = 0; rg < 16; rg++) {
    const int qr = (rg & 3) + 8 * (rg >> 2) + 4 * hh;  // local q-row of this reg
    float iv = __shfl(inv, qr);
    const size_t rowoff = base + (size_t)(q0w + qr) * 1024;
    ctxb[rowoff + l31] = f2bf(o0[rg] * iv);
    ctxb[rowoff + 32 + l31] = f2bf(o1[rg] * iv);
  }
}

// ---------------- fused residual + split-K reduce (bf16 partials) + LayerNorm ----------------
// out = LN(a + b + c) * g + be ;  a is fp32 (ABF=0) or bf16 (ABF=1); b,c bf16 partials
template <int ABF>
__global__ __launch_bounds__(256) void ln_kernel(const void* __restrict__ a,
                                                 const u16* __restrict__ b,
                                                 const u16* __restrict__ c,
                                                 const float* __restrict__ g,
                                                 const float* __restrict__ be,
                                                 float* __restrict__ of32,
                                                 u16* __restrict__ obf) {
  const int row = blockIdx.x;
  const int tid = threadIdx.x;
  const size_t base = (size_t)row * 1024;
  const int cc = tid * 4;
  float a0, a1, a2, a3;
  if (ABF) {
    uint2 ua = *(const uint2*)((const u16*)a + base + cc);
    a0 = bf2f(ua.x & 0xffff); a1 = bf2f(ua.x >> 16);
    a2 = bf2f(ua.y & 0xffff); a3 = bf2f(ua.y >> 16);
  } else {
    float4 xa = *(const float4*)((const float*)a + base + cc);
    a0 = xa.x; a1 = xa.y; a2 = xa.z; a3 = xa.w;
  }
  uint2 ub = *(const uint2*)(b + base + cc);
  uint2 uc = *(const uint2*)(c + base + cc);
  float v0 = a0 + bf2f(ub.x & 0xffff) + bf2f(uc.x & 0xffff);
  float v1 = a1 + bf2f(ub.x >> 16)    + bf2f(uc.x >> 16);
  float v2 = a2 + bf2f(ub.y & 0xffff) + bf2f(uc.y & 0xffff);
  float v3 = a3 + bf2f(ub.y >> 16)    + bf2f(uc.y >> 16);
  float s1 = v0 + v1 + v2 + v3;
  float s2 = v0 * v0 + v1 * v1 + v2 * v2 + v3 * v3;
  for (int off = 1; off < 64; off <<= 1) {
    s1 += __shfl_xor(s1, off);
    s2 += __shfl_xor(s2, off);
  }
  __shared__ float red[8];
  int wv = tid >> 6;
  if ((tid & 63) == 0) { red[wv] = s1; red[4 + wv] = s2; }
  __syncthreads();
  s1 = red[0] + red[1] + red[2] + red[3];
  s2 = red[4] + red[5] + red[6] + red[7];
  float mu = s1 * (1.0f / 1024.0f);
  float var = s2 * (1.0f / 1024.0f) - mu * mu;
  float rs = rsqrtf(var + 1e-5f);
  float4 gv = *(const float4*)(g + cc);
  float4 bev = *(const float4*)(be + cc);
  float y0 = (v0 - mu) * rs * gv.x + bev.x;
  float y1 = (v1 - mu) * rs * gv.y + bev.y;
  float y2 = (v2 - mu) * rs * gv.z + bev.z;
  float y3 = (v3 - mu) * rs * gv.w + bev.w;
  if (of32) {
    float4 o = make_float4(y0, y1, y2, y3);
    *(float4*)(of32 + base + cc) = o;
  }
  if (obf) {
    uint2 o;
    o.x = (u32)f2bf(y0) | ((u32)f2bf(y1) << 16);
    o.y = (u32)f2bf(y2) | ((u32)f2bf(y3) << 16);
    *(uint2*)(obf + base + cc) = o;
  }
}

// ---------------- launch ----------------
extern "C" void kernel_launch(void* const* d_in, const int* in_sizes, int n_in,
                              void* d_out, int out_size, void* d_ws, size_t ws_size,
                              hipStream_t stream) {
  const int Mtok = 8192, D = 1024, F = 4096, T = 2048;
  const float* x   = (const float*)d_in[0];
  const float* WQ  = (const float*)d_in[1];
  const float* bQ  = (const float*)d_in[2];
  const float* WK  = (const float*)d_in[3];
  const float* bK  = (const float*)d_in[4];
  const float* WV  = (const float*)d_in[5];
  const float* bV  = (const float*)d_in[6];
  const float* WO  = (const float*)d_in[7];
  const float* bO  = (const float*)d_in[8];
  const float* W1  = (const float*)d_in[9];
  const float* b1  = (const float*)d_in[10];
  const float* W2  = (const float*)d_in[11];
  const float* b2  = (const float*)d_in[12];
  const float* g1  = (const float*)d_in[13];
  const float* be1 = (const float*)d_in[14];
  const float* g2  = (const float*)d_in[15];
  const float* be2 = (const float*)d_in[16];

  char* ws = (char*)d_ws;
  const size_t MB = 1024 * 1024;
  u16*  xb     = (u16*)(ws + 0);          // 16 MB (dead after QKV)
  u16*  wqkvb  = (u16*)(ws + 16 * MB);    // 6 MB  (dead after QKV)
  u16*  wob    = (u16*)(ws + 22 * MB);    // 2 MB  (dead after WO)
  u16*  w1b    = (u16*)(ws + 24 * MB);    // 8 MB  (dead after FF1)
  u16*  w2b    = (u16*)(ws + 32 * MB);    // 8 MB  (dead after FF2)
  u16*  qb     = (u16*)(ws + 40 * MB);    // 16 MB (dead after attn)
  u16*  kb     = (u16*)(ws + 56 * MB);    // 16 MB (dead after attn)
  u16*  vtb    = (u16*)(ws + 72 * MB);    // 16 MB, written transposed by QKV (dead after attn)
  u16*  ctxb   = (u16*)(ws + 88 * MB);    // 16 MB (dead after WO)
  u16*  wp0    = (u16*)(ws + 104 * MB);   // 16 MB bf16 partial (dead after ln1)
  u16*  wp1    = (u16*)(ws + 120 * MB);   // 16 MB bf16 partial (dead after ln1)
  u16*  h1b    = (u16*)(ws + 136 * MB);   // 16 MB bf16 LN1 output (live until ln2)
  u16*  ff1b   = (u16*)(ws + 40 * MB);    // 64 MB over qb..ctxb (dead after FF2)
  u16*  fp0    = (u16*)(ws + 0);          // 16 MB bf16 partial over xb
  u16*  fp1    = (u16*)(ws + 16 * MB);    // 16 MB bf16 partial over wqkvb/wob
  float* out   = (float*)d_out;

  dim3 blk(256);
  dim3 blk512(512);
  cvt_all<<<(20 << 20) / 1024, blk, 0, stream>>>(x, WQ, WK, WV, WO, W1, W2,
                                                 xb, wqkvb, wob, w1b, w2b);

  // fused QKV (N=3072): seg0=Q scaled log2(e)/8, seg1=K, seg2=V stored transposed
  gemm256<0, 1, 0><<<dim3(768), blk512, 0, stream>>>(xb, wqkvb, bQ, qb, Mtok, 3072, D,
                                                     bK, kb, bV, vtb, 24);
  attn_mfma<<<dim3(1024), blk, 0, stream>>>(qb, kb, vtb, ctxb, T);

  // WO projection, split-K=2 -> bf16 partials wp0/wp1; ln1 reduces
  gemm256<0, 0, 1><<<dim3(512), blk512, 0, stream>>>(ctxb, wob, bO, wp0, Mtok, D, D,
                                                     nullptr, wp1, nullptr, nullptr, 8);
  ln_kernel<0><<<Mtok, blk, 0, stream>>>(x, wp0, wp1, g1, be1, nullptr, h1b);

  gemm256<1, 0, 0><<<dim3(1024), blk512, 0, stream>>>(h1b, w1b, b1, ff1b, Mtok, F, D,
                                                      nullptr, nullptr, nullptr, nullptr, 32);
  // FF2, split-K=2 -> bf16 partials fp0/fp1; ln2 reduces (bf16 residual h1b)
  gemm256<0, 0, 1><<<dim3(512), blk512, 0, stream>>>(ff1b, w2b, b2, fp0, Mtok, D, F,
                                                     nullptr, fp1, nullptr, nullptr, 8);
  ln_kernel<1><<<Mtok, blk, 0, stream>>>(h1b, fp0, fp1, g2, be2, out, (u16*)nullptr);
}